// Round 1
// baseline (637.562 us; speedup 1.0000x reference)
//
#include <hip/hip_runtime.h>

// GAT aggregate: N=100000 nodes, K=16 neighbors, D=128, DOUT=128, all fp32.
// out[n] = relu( softmax([<self,neigh_k>]_{k=0..K}) . [neigh;self] @ W )
//
// One wave (64 lanes) per node; lane l owns feature dims {2l, 2l+1}.
// W staged in LDS once per block, interleaved so one ds_read_b128 serves
// two d-rows x two output columns.

constexpr int K    = 16;
constexpr int D    = 128;
constexpr int DOUT = 128;

__launch_bounds__(256, 2)
__global__ void gat_kernel(const float* __restrict__ self_vecs,
                           const float* __restrict__ neigh_vecs,
                           const float* __restrict__ W,
                           float* __restrict__ out,
                           int n_nodes, int total_waves) {
    // Interleaved W: float4 slot s = p*64 + l holds
    //   { W[2p][2l], W[2p][2l+1], W[2p+1][2l], W[2p+1][2l+1] }
    __shared__ float Ws[D * DOUT];  // 64 KiB

    const int tid = threadIdx.x;

    // ---- stage W into LDS (coalesced float2 reads from two rows) ----
    for (int s = tid; s < (D * DOUT) / 4; s += blockDim.x) {
        const int p = s >> 6;
        const int l = s & 63;
        const float* r0 = W + (size_t)(2 * p) * DOUT + 2 * l;
        const float2 a = *(const float2*)r0;
        const float2 b = *(const float2*)(r0 + DOUT);
        ((float4*)Ws)[s] = make_float4(a.x, a.y, b.x, b.y);
    }
    __syncthreads();

    const int lane = tid & 63;
    const int wid  = tid >> 6;
    const int wave_global = blockIdx.x * (blockDim.x >> 6) + wid;

    for (int n = wave_global; n < n_nodes; n += total_waves) {
        // ---- load self + 16 neighbors (float2 per lane, coalesced) ----
        const float2 sv = *(const float2*)(self_vecs + (size_t)n * D + 2 * lane);
        float2 v[K + 1];
        const float* nb = neigh_vecs + (size_t)n * K * D + 2 * lane;
        #pragma unroll
        for (int k = 0; k < K; ++k)
            v[k] = *(const float2*)(nb + (size_t)k * D);
        v[K] = sv;

        // ---- 17 dot products, butterfly-reduced (scores end up in ALL lanes) ----
        float s[K + 1];
        #pragma unroll
        for (int k = 0; k <= K; ++k) {
            float p = sv.x * v[k].x + sv.y * v[k].y;
            #pragma unroll
            for (int off = 32; off; off >>= 1)
                p += __shfl_xor(p, off);
            s[k] = p;
        }

        // ---- stable softmax (self-score ~128 => exp would overflow without max-sub) ----
        float m = s[0];
        #pragma unroll
        for (int k = 1; k <= K; ++k) m = fmaxf(m, s[k]);
        float sum = 0.f;
        #pragma unroll
        for (int k = 0; k <= K; ++k) {
            const float e = __expf(s[k] - m);
            s[k] = e;
            sum += e;
        }
        const float inv = 1.0f / sum;

        // ---- context (fold the 1/sum into a single final scale) ----
        float cx = 0.f, cy = 0.f;
        #pragma unroll
        for (int k = 0; k <= K; ++k) {
            cx += s[k] * v[k].x;
            cy += s[k] * v[k].y;
        }
        cx *= inv; cy *= inv;

        // ---- out[2l..2l+1] = relu( sum_d ctx[d] * W[d][2l..2l+1] ) ----
        // ctx[2p] lives in lane p's cx, ctx[2p+1] in lane p's cy;
        // compile-time lane index => v_readlane broadcast (SGPR operand).
        float acc0 = 0.f, acc1 = 0.f;
        #pragma unroll
        for (int p = 0; p < D / 2; ++p) {
            const float c0 = __shfl(cx, p);
            const float c1 = __shfl(cy, p);
            const float4 w = ((const float4*)Ws)[p * 64 + lane];
            acc0 += c0 * w.x + c1 * w.z;
            acc1 += c0 * w.y + c1 * w.w;
        }
        *(float2*)(out + (size_t)n * DOUT + 2 * lane) =
            make_float2(fmaxf(acc0, 0.f), fmaxf(acc1, 0.f));
    }
}

extern "C" void kernel_launch(void* const* d_in, const int* in_sizes, int n_in,
                              void* d_out, int out_size, void* d_ws, size_t ws_size,
                              hipStream_t stream) {
    const float* self_vecs = (const float*)d_in[0];
    const float* neigh     = (const float*)d_in[1];
    const float* W         = (const float*)d_in[2];
    float* out = (float*)d_out;

    const int n_nodes = in_sizes[0] / D;  // 100000

    const int tpb = 256;                  // 4 waves
    const int blocks = 512;               // 2 blocks/CU x 256 CU = exact residency (64KB LDS each)
    const int total_waves = blocks * (tpb / 64);

    gat_kernel<<<dim3(blocks), dim3(tpb), 0, stream>>>(
        self_vecs, neigh, W, out, n_nodes, total_waves);
}